// Round 1
// baseline (100.777 us; speedup 1.0000x reference)
//
#include <hip/hip_runtime.h>

// Count elements where x < y over n4 float4s, accumulate into *cnt.
__global__ __launch_bounds__(256) void wrr_count_kernel(
    const float4* __restrict__ x, const float4* __restrict__ y,
    unsigned int* __restrict__ cnt, int n4) {
    int tid    = blockIdx.x * blockDim.x + threadIdx.x;
    int stride = gridDim.x * blockDim.x;

    unsigned int c = 0;
    for (int i = tid; i < n4; i += stride) {
        float4 a = x[i];
        float4 b = y[i];
        c += (a.x < b.x);
        c += (a.y < b.y);
        c += (a.z < b.z);
        c += (a.w < b.w);
    }

    // Wave-64 butterfly reduce.
    #pragma unroll
    for (int off = 32; off > 0; off >>= 1)
        c += __shfl_down(c, off);

    // Block reduce across the 4 waves, one atomic per block.
    __shared__ unsigned int s[4];
    int lane = threadIdx.x & 63;
    int wave = threadIdx.x >> 6;
    if (lane == 0) s[wave] = c;
    __syncthreads();
    if (threadIdx.x == 0) {
        unsigned int t = s[0] + s[1] + s[2] + s[3];
        atomicAdd(cnt, t);
    }
}

__global__ void wrr_finalize_kernel(const unsigned int* __restrict__ cnt,
                                    float* __restrict__ out, float inv_n) {
    out[0] = 1.0f - (float)(*cnt) * inv_n;
}

extern "C" void kernel_launch(void* const* d_in, const int* in_sizes, int n_in,
                              void* d_out, int out_size, void* d_ws, size_t ws_size,
                              hipStream_t stream) {
    const float* x = (const float*)d_in[0];
    const float* y = (const float*)d_in[1];
    float* out = (float*)d_out;
    unsigned int* cnt = (unsigned int*)d_ws;

    const long long n = (long long)in_sizes[0];  // 64,000,000 (divisible by 4)
    const int n4 = (int)(n / 4);

    // d_ws is poisoned (0xAA) once and never re-poisoned between timed
    // replays — zero the counter on-stream every call (graph-capture safe).
    hipMemsetAsync(cnt, 0, sizeof(unsigned int), stream);

    const int block = 256;
    const int grid  = 2048;  // 256 CU × 8 blocks/CU; grid-stride covers the rest
    wrr_count_kernel<<<grid, block, 0, stream>>>(
        (const float4*)x, (const float4*)y, cnt, n4);

    wrr_finalize_kernel<<<1, 1, 0, stream>>>(cnt, out, 1.0f / (float)n);
}